// Round 7
// baseline (226.427 us; speedup 1.0000x reference)
//
#include <hip/hip_runtime.h>
#include <stdint.h>

typedef unsigned long long u64;
typedef unsigned int u32;
typedef float vf2 __attribute__((ext_vector_type(2)));

constexpr int Ccand = 32;   // candidates per row
constexpr int Evoc  = 512;  // vocab size
constexpr int Tgt   = 64;   // target_size

// descending bitonic sort of one f32 per lane across the 64-lane wave
__device__ __forceinline__ void sort64_desc_f32(float& a, int lane) {
    #pragma unroll
    for (int k2 = 2; k2 <= 64; k2 <<= 1) {
        #pragma unroll
        for (int j = k2 >> 1; j > 0; j >>= 1) {
            float o = __shfl_xor(a, j);
            bool lower = (lane & j) == 0;
            bool keepMax = ((lane & k2) == 0) ? lower : !lower;
            bool g = a > o;
            a = (keepMax == g) ? a : o;
        }
    }
}

// descending bitonic sort of one u64 key per lane across the wave
__device__ __forceinline__ void sort64_desc_u64(u64& a, int lane) {
    #pragma unroll
    for (int k2 = 2; k2 <= 64; k2 <<= 1) {
        #pragma unroll
        for (int j = k2 >> 1; j > 0; j >>= 1) {
            u64 o = __shfl_xor(a, j);
            bool lower = (lane & j) == 0;
            bool keepMax = ((lane & k2) == 0) ? lower : !lower;
            bool g = a > o;
            a = (keepMax == g) ? a : o;
        }
    }
}

// One wave (64 lanes) per row. Lane l owns cols {4l..4l+3} and {256+4l..+3}.
__global__ __launch_bounds__(256, 4) void cooc_expand(
    const int* __restrict__ cand_ids,
    const float* __restrict__ cand_scores,
    const float* __restrict__ cooc,
    float* __restrict__ out_ids,
    float* __restrict__ out_scores,
    int B)
{
    const int lane = threadIdx.x & 63;
    const int wid  = threadIdx.x >> 6;
    const int row  = blockIdx.x * 4 + wid;
    __shared__ u64 buf[4][512];    // per-wave survivor buffer (worst case 512)
    if (row >= B) return;   // never taken (B % 4 == 0); no block barriers used

    // ---- load candidates (lanes 0..31) ----
    int   my_id = -1;
    float my_s  = 0.0f;
    if (lane < Ccand) {
        my_id = cand_ids[(size_t)row * Ccand + lane];
        my_s  = cand_scores[(size_t)row * Ccand + lane];
    }

    // ---- dup-merge via 32-wide bitonic sort on key=(id<<5)|lane ----
    // sorted order = (id asc, orig-lane asc); dups adjacent; pair-sum is
    // exactly np.add.at's left-assoc ascending-i order for groups <= 2.
    u32   key = (lane < Ccand) ? (((u32)my_id << 5) | (u32)lane) : 0x7FFFFFFFu;
    float sv  = my_s;
    const int l5 = lane & 31;
    #pragma unroll
    for (int k2 = 2; k2 <= 32; k2 <<= 1) {
        #pragma unroll
        for (int j = k2 >> 1; j > 0; j >>= 1) {
            u32   ok = __shfl_xor(key, j);
            float os = __shfl_xor(sv, j);
            bool lower   = (l5 & j) == 0;
            bool keepMin = ((l5 & k2) == 0) ? lower : !lower;
            bool g = key < ok;
            bool keep = (g == keepMin);
            key = keep ? key : ok;
            sv  = keep ? sv  : os;
        }
    }
    int sid = (int)(key >> 5);
    u32 kprev  = __shfl_up(key, 1);    // lane0 keeps own
    u32 kprev2 = __shfl_up(key, 2);
    u32 knext  = __shfl_down(key, 1);  // lane63 keeps own
    float snext = __shfl_down(sv, 1);
    int idprev  = (int)(kprev  >> 5);
    int idprev2 = (int)(kprev2 >> 5);
    int idnext  = (int)(knext  >> 5);
    bool isFirst = (lane == 0) || (sid != idprev);
    bool hasPair = (lane < 31) && (idnext == sid);
    float ssum = sv + (hasPair ? snext : 0.0f);
    bool third = (lane >= 2) && (lane < Ccand) && (sid == idprev) && (sid == idprev2);
    bool anyTriple = (__ballot(third) != 0ull);   // wave-uniform

    int sorted_id, sorted_sb, m;
    if (!anyTriple) {
        // fast path (~98% of rows)
        bool flag = (lane < Ccand) && isFirst;
        int f = flag ? 1 : 0;
        u32 inc = (u32)f;
        #pragma unroll
        for (int i = 1; i < 64; i <<= 1) {
            u32 t2 = __shfl_up(inc, i);
            if (lane >= i) inc += t2;
        }
        m = __builtin_amdgcn_readlane((int)inc, 63);
        int dstl = flag ? ((int)inc - 1) : 63;   // park non-firsts at 63 (>= m)
        sorted_id = __builtin_amdgcn_ds_permute(dstl << 2, sid);
        sorted_sb = __builtin_amdgcn_ds_permute(dstl << 2, __float_as_int(ssum));
    } else {
        // exact slow path: original serial merge (any group size)
        int first = 64; float sm = 0.0f;
        #pragma unroll
        for (int j = 0; j < Ccand; ++j) {
            int   idj = __shfl(my_id, j);
            float sj  = __shfl(my_s,  j);
            bool match = (idj == my_id);
            if (match && j < first) first = j;
            sm += match ? sj : 0.0f;
        }
        bool alive = (lane < Ccand) && (first == lane);
        u64 ab = __ballot(alive);
        m = __popcll(ab);
        int rk = 0;
        #pragma unroll
        for (int j = 0; j < Ccand; ++j) {
            int idj = __shfl(my_id, j);
            bool aj = (ab >> j) & 1ull;
            rk += (aj && idj < my_id) ? 1 : 0;
        }
        int dstl = alive ? rk : ((lane < 32) ? (lane + 32) : lane);
        sorted_id = __builtin_amdgcn_ds_permute(dstl << 2, my_id);
        sorted_sb = __builtin_amdgcn_ds_permute(dstl << 2, __float_as_int(sm));
    }

    // ---- accumulation: 4 iters x 8 ids; readlane -> SGPR base addr;
    // packed v_pk_fma_f32 (bit-exact per component); t>=m: s=0,
    // fma(0,·,acc)==acc bit-exact (acc stays >= +0).
    vf2 acc2[4];
    acc2[0] = (vf2){0.f, 0.f}; acc2[1] = (vf2){0.f, 0.f};
    acc2[2] = (vf2){0.f, 0.f}; acc2[3] = (vf2){0.f, 0.f};
    u32 maskbits = 0;
    const int l4 = lane << 2;
    #pragma unroll 1
    for (int t = 0; t < 32; t += 8) {
        int   e[8];
        float s[8];
        #pragma unroll
        for (int u = 0; u < 8; ++u) {
            e[u] = __builtin_amdgcn_readlane(sorted_id, t + u) & 511;
            s[u] = (t + u < m) ? __int_as_float(__builtin_amdgcn_readlane(sorted_sb, t + u)) : 0.0f;
        }
        float4 A[8], Bv[8];
        #pragma unroll
        for (int u = 0; u < 8; ++u) {
            const float* rp = cooc + ((size_t)e[u] << 9);
            A[u]  = *reinterpret_cast<const float4*>(rp + l4);
            Bv[u] = *reinterpret_cast<const float4*>(rp + 256 + l4);
        }
        #pragma unroll
        for (int u = 0; u < 8; ++u) {
            vf2 sv2; sv2[0] = s[u]; sv2[1] = s[u];
            vf2 a0; a0[0] = A[u].x;  a0[1] = A[u].y;
            vf2 a1; a1[0] = A[u].z;  a1[1] = A[u].w;
            vf2 b0; b0[0] = Bv[u].x; b0[1] = Bv[u].y;
            vf2 b1; b1[0] = Bv[u].z; b1[1] = Bv[u].w;
            acc2[0] = __builtin_elementwise_fma(sv2, a0, acc2[0]);
            acc2[1] = __builtin_elementwise_fma(sv2, a1, acc2[1]);
            acc2[2] = __builtin_elementwise_fma(sv2, b0, acc2[2]);
            acc2[3] = __builtin_elementwise_fma(sv2, b1, acc2[3]);
        }
        // masked-slot bookkeeping (reference: cooc_scores[b, e] = -inf);
        // e is wave-uniform (SGPR), owner/bit computed scalar-side.
        #pragma unroll
        for (int u = 0; u < 8; ++u) {
            if ((t + u < m) && (((e[u] & 255) >> 2) == lane))
                maskbits |= 1u << (((e[u] >> 8) << 2) | (e[u] & 3));
        }
    }

    // ---- original-layout values; masked -> -1.0 (strictly below all) ----
    float v[8];
    v[0] = acc2[0][0]; v[1] = acc2[0][1]; v[2] = acc2[1][0]; v[3] = acc2[1][1];
    v[4] = acc2[2][0]; v[5] = acc2[2][1]; v[6] = acc2[3][0]; v[7] = acc2[3][1];
    #pragma unroll
    for (int j = 0; j < 8; ++j)
        if ((maskbits >> j) & 1u) v[j] = -1.0f;

    // ---- L32: 32nd largest of per-lane maxima; T >= L32 and every
    // top-32 element (incl. ==T ties) has v >= L32 ----
    float mx8 = v[0];
    #pragma unroll
    for (int j = 1; j < 8; ++j) mx8 = fmaxf(mx8, v[j]);
    float srt = mx8;
    sort64_desc_f32(srt, lane);
    float L32 = __int_as_float(__builtin_amdgcn_readlane(__float_as_int(srt), 31));

    // ---- survivor count + exclusive scan for LDS slots ----
    int cnt = 0;
    #pragma unroll
    for (int j = 0; j < 8; ++j) cnt += (v[j] >= L32) ? 1 : 0;
    u32 sincl = (u32)cnt;
    #pragma unroll
    for (int i = 1; i < 64; i <<= 1) {
        u32 t2 = __shfl_up(sincl, i);
        if (lane >= i) sincl += t2;
    }
    int sbase = (int)sincl - cnt;
    int S_tot = __builtin_amdgcn_readlane((int)sincl, 63);

    // ---- scatter survivor keys (valbits<<32 | 511-col): unique keys,
    // desc u64 order == np stable top-k order (value desc, col asc) ----
    int slot = sbase;
    #pragma unroll
    for (int j = 0; j < 8; ++j) {
        bool s = (v[j] >= L32);
        if (s) {
            int col = (j < 4) ? (l4 + j) : (256 + l4 + (j - 4));
            buf[wid][slot] = ((u64)__float_as_uint(v[j]) << 32) | (u32)(511 - col);
        }
        slot += s ? 1 : 0;
    }
    __threadfence_block();   // LDS visibility within the wave

    u64 k;
    if (S_tot <= 64) {
        // common path (~99.98% of rows): one 64-wide u64 bitonic sort.
        k = (lane < S_tot) ? buf[wid][lane] : 0ull;
        sort64_desc_u64(k, lane);
    } else {
        // rare exact fallback: chunked sort + merge keep-top-64
        u64 cur = (lane < S_tot) ? buf[wid][lane] : 0ull;
        sort64_desc_u64(cur, lane);
        for (int base = 64; base < S_tot; base += 64) {
            u64 nxt = (base + lane < S_tot) ? buf[wid][base + lane] : 0ull;
            sort64_desc_u64(nxt, lane);
            u64 o = __shfl_xor(nxt, 63);           // nxt[63-lane]
            cur = (cur >= o) ? cur : o;            // top-64 of 128, bitonic
            #pragma unroll
            for (int j = 32; j > 0; j >>= 1) {     // descending cleanup
                u64 p = __shfl_xor(cur, j);
                bool keepMax = (lane & j) == 0;
                bool g = cur > p;
                cur = (keepMax == g) ? cur : p;
            }
        }
        k = cur;
    }
    // lane r now holds rank-r key (r < 32 are the selected top-32)

    // ---- coalesced stores: [orig 32 | selected 32] ----
    int src = (lane >= 32) ? (lane - 32) : 0;
    u64 kk = __shfl(k, src);
    const size_t ob = (size_t)row * Tgt;
    float oid, osc;
    if (lane < Ccand) {
        oid = (float)my_id;
        osc = my_s;
    } else {
        oid = (float)(int)(511 - (u32)(kk & 511ull));
        osc = __uint_as_float((u32)(kk >> 32));
    }
    out_ids[ob + lane]    = oid;
    out_scores[ob + lane] = osc;
}

extern "C" void kernel_launch(void* const* d_in, const int* in_sizes, int n_in,
                              void* d_out, int out_size, void* d_ws, size_t ws_size,
                              hipStream_t stream) {
    const int*   ids    = (const int*)d_in[0];
    const float* scores = (const float*)d_in[1];
    const float* cooc   = (const float*)d_in[2];
    int B = in_sizes[0] / Ccand;
    float* out_ids    = (float*)d_out;
    float* out_scores = out_ids + (size_t)B * Tgt;
    int blocks = (B + 3) / 4;
    hipLaunchKernelGGL(cooc_expand, dim3(blocks), dim3(256), 0, stream,
                       ids, scores, cooc, out_ids, out_scores, B);
}

// Round 8
// 209.704 us; speedup vs baseline: 1.0797x; 1.0797x over previous
//
#include <hip/hip_runtime.h>
#include <stdint.h>

typedef unsigned long long u64;
typedef unsigned int u32;
typedef float vf2 __attribute__((ext_vector_type(2)));

constexpr int Ccand = 32;   // candidates per row
constexpr int Evoc  = 512;  // vocab size
constexpr int Tgt   = 64;   // target_size

// descending bitonic sort of one f32 per lane across the 64-lane wave
__device__ __forceinline__ void sort64_desc_f32(float& a, int lane) {
    #pragma unroll
    for (int k2 = 2; k2 <= 64; k2 <<= 1) {
        #pragma unroll
        for (int j = k2 >> 1; j > 0; j >>= 1) {
            float o = __shfl_xor(a, j);
            bool lower = (lane & j) == 0;
            bool keepMax = ((lane & k2) == 0) ? lower : !lower;
            bool g = a > o;
            a = (keepMax == g) ? a : o;
        }
    }
}

// descending bitonic sort of one u64 key per lane across the wave
__device__ __forceinline__ void sort64_desc_u64(u64& a, int lane) {
    #pragma unroll
    for (int k2 = 2; k2 <= 64; k2 <<= 1) {
        #pragma unroll
        for (int j = k2 >> 1; j > 0; j >>= 1) {
            u64 o = __shfl_xor(a, j);
            bool lower = (lane & j) == 0;
            bool keepMax = ((lane & k2) == 0) ? lower : !lower;
            bool g = a > o;
            a = (keepMax == g) ? a : o;
        }
    }
}

// One wave (64 lanes) per row. Lane l owns cols {4l..4l+3} and {256+4l..+3}.
__global__ __launch_bounds__(256, 8) void cooc_expand(
    const int* __restrict__ cand_ids,
    const float* __restrict__ cand_scores,
    const float* __restrict__ cooc,
    float* __restrict__ out_ids,
    float* __restrict__ out_scores,
    int B)
{
    const int lane = threadIdx.x & 63;
    const int wid  = threadIdx.x >> 6;
    const int row  = blockIdx.x * 4 + wid;
    __shared__ u64 buf[4][64];   // per-wave 64-slot window (2 KB/block)
    if (row >= B) return;   // never taken (B % 4 == 0); no block barriers used

    // ---- load candidates (lanes 0..31) ----
    int   my_id = -1;
    float my_s  = 0.0f;
    if (lane < Ccand) {
        my_id = cand_ids[(size_t)row * Ccand + lane];
        my_s  = cand_scores[(size_t)row * Ccand + lane];
    }

    // ---- duplicate merge, np.add.at order (ascending i, from 0.0) ----
    int   first = 64;
    float sm    = 0.0f;
    #pragma unroll
    for (int j = 0; j < Ccand; ++j) {
        int   idj = __shfl(my_id, j);   // const lane -> readlane
        float sj  = __shfl(my_s,  j);
        bool match = (idj == my_id);
        if (match && j < first) first = j;
        sm += match ? sj : 0.0f;
    }
    bool alive = (lane < Ccand) && (first == lane);
    u64 aball = __ballot(alive);
    int m = __popcll(aball);

    // ---- rank alive entries by ascending id (alive ids distinct) ----
    int rk = 0;
    #pragma unroll
    for (int j = 0; j < Ccand; ++j) {
        int idj = __shfl(my_id, j);
        bool aj = (aball >> j) & 1ull;
        rk += (aj && idj < my_id) ? 1 : 0;
    }
    int dst = alive ? rk : ((lane < 32) ? (lane + 32) : lane);
    int sorted_id = __builtin_amdgcn_ds_permute(dst << 2, my_id);
    int sorted_sb = __builtin_amdgcn_ds_permute(dst << 2, __float_as_int(sm));

    // ---- accumulation: 8 iters x 4 ids; readlane -> SGPR base addr;
    // packed v_pk_fma_f32 (bit-exact per component); t>=m: s=0,
    // fma(0,·,acc)==acc bit-exact (acc stays >= +0).
    vf2 acc2[4];
    acc2[0] = (vf2){0.f, 0.f}; acc2[1] = (vf2){0.f, 0.f};
    acc2[2] = (vf2){0.f, 0.f}; acc2[3] = (vf2){0.f, 0.f};
    u32 maskbits = 0;
    const int l4 = lane << 2;
    #pragma unroll 1
    for (int t = 0; t < 32; t += 4) {
        int   e[4];
        float s[4];
        #pragma unroll
        for (int u = 0; u < 4; ++u) {
            e[u] = __builtin_amdgcn_readlane(sorted_id, t + u) & 511;
            s[u] = (t + u < m) ? __int_as_float(__builtin_amdgcn_readlane(sorted_sb, t + u)) : 0.0f;
        }
        float4 A[4], Bv[4];
        #pragma unroll
        for (int u = 0; u < 4; ++u) {
            const float* rp = cooc + ((size_t)e[u] << 9);
            A[u]  = *reinterpret_cast<const float4*>(rp + l4);
            Bv[u] = *reinterpret_cast<const float4*>(rp + 256 + l4);
        }
        #pragma unroll
        for (int u = 0; u < 4; ++u) {
            vf2 sv2; sv2[0] = s[u]; sv2[1] = s[u];
            vf2 a0; a0[0] = A[u].x;  a0[1] = A[u].y;
            vf2 a1; a1[0] = A[u].z;  a1[1] = A[u].w;
            vf2 b0; b0[0] = Bv[u].x; b0[1] = Bv[u].y;
            vf2 b1; b1[0] = Bv[u].z; b1[1] = Bv[u].w;
            acc2[0] = __builtin_elementwise_fma(sv2, a0, acc2[0]);
            acc2[1] = __builtin_elementwise_fma(sv2, a1, acc2[1]);
            acc2[2] = __builtin_elementwise_fma(sv2, b0, acc2[2]);
            acc2[3] = __builtin_elementwise_fma(sv2, b1, acc2[3]);
        }
        // masked-slot bookkeeping (reference: cooc_scores[b, e] = -inf)
        #pragma unroll
        for (int u = 0; u < 4; ++u) {
            if ((t + u < m) && (((e[u] & 255) >> 2) == lane))
                maskbits |= 1u << (((e[u] >> 8) << 2) | (e[u] & 3));
        }
    }

    // ---- original-layout values; masked -> -1.0 (strictly below all) ----
    float v[8];
    v[0] = acc2[0][0]; v[1] = acc2[0][1]; v[2] = acc2[1][0]; v[3] = acc2[1][1];
    v[4] = acc2[2][0]; v[5] = acc2[2][1]; v[6] = acc2[3][0]; v[7] = acc2[3][1];
    #pragma unroll
    for (int j = 0; j < 8; ++j)
        if ((maskbits >> j) & 1u) v[j] = -1.0f;

    // ---- L32: 32nd largest of per-lane maxima; T >= L32 and every
    // top-32 element (incl. ==T ties) has v >= L32; also S_tot >= 32 ----
    float mx8 = v[0];
    #pragma unroll
    for (int j = 1; j < 8; ++j) mx8 = fmaxf(mx8, v[j]);
    float srt = mx8;
    sort64_desc_f32(srt, lane);
    float L32 = __int_as_float(__builtin_amdgcn_readlane(__float_as_int(srt), 31));

    // ---- survivor count + exclusive scan for global slots ----
    int cnt = 0;
    #pragma unroll
    for (int j = 0; j < 8; ++j) cnt += (v[j] >= L32) ? 1 : 0;
    u32 sincl = (u32)cnt;
    #pragma unroll
    for (int i = 1; i < 64; i <<= 1) {
        u32 t2 = __shfl_up(sincl, i);
        if (lane >= i) sincl += t2;
    }
    int sbase = (int)sincl - cnt;
    int S_tot = __builtin_amdgcn_readlane((int)sincl, 63);

    // ---- chunked scatter + sort + merge-prune over 64-slot windows.
    // Chunk 0 is the whole story for ~99.98% of rows (S_tot <= 64).
    // Keys (valbits<<32 | 511-col) unique; desc u64 order == np stable
    // top-k order (value desc, col asc). ----
    int nchunk = (S_tot + 63) >> 6;   // wave-uniform >= 1
    u64 cur = 0ull;
    #pragma unroll 1
    for (int c = 0; c < nchunk; ++c) {
        const int lo = c << 6;
        // scatter survivors whose slot falls in [lo, lo+64)
        int slot = sbase;
        #pragma unroll
        for (int j = 0; j < 8; ++j) {
            bool s = (v[j] >= L32);
            int  rel = slot - lo;
            if (s && rel >= 0 && rel < 64) {
                int col = (j < 4) ? (l4 + j) : (256 + l4 + (j - 4));
                buf[wid][rel] = ((u64)__float_as_uint(v[j]) << 32) | (u32)(511 - col);
            }
            slot += s ? 1 : 0;
        }
        __threadfence_block();
        u64 nxt = (lo + lane < S_tot) ? buf[wid][lane] : 0ull;
        __threadfence_block();   // reads complete before next chunk's writes
        sort64_desc_u64(nxt, lane);
        if (c == 0) {
            cur = nxt;
        } else {
            u64 o = __shfl_xor(nxt, 63);           // nxt[63-lane]
            cur = (cur >= o) ? cur : o;            // top-64 of 128, bitonic
            #pragma unroll
            for (int j = 32; j > 0; j >>= 1) {     // descending cleanup
                u64 p = __shfl_xor(cur, j);
                bool keepMax = (lane & j) == 0;
                bool g = cur > p;
                cur = (keepMax == g) ? cur : p;
            }
        }
    }
    // lane r now holds rank-r key (r < 32 are the selected top-32)

    // ---- coalesced stores: [orig 32 | selected 32] ----
    int src = (lane >= 32) ? (lane - 32) : 0;
    u64 kk = __shfl(cur, src);
    const size_t ob = (size_t)row * Tgt;
    float oid, osc;
    if (lane < Ccand) {
        oid = (float)my_id;
        osc = my_s;
    } else {
        oid = (float)(int)(511 - (u32)(kk & 511ull));
        osc = __uint_as_float((u32)(kk >> 32));
    }
    out_ids[ob + lane]    = oid;
    out_scores[ob + lane] = osc;
}

extern "C" void kernel_launch(void* const* d_in, const int* in_sizes, int n_in,
                              void* d_out, int out_size, void* d_ws, size_t ws_size,
                              hipStream_t stream) {
    const int*   ids    = (const int*)d_in[0];
    const float* scores = (const float*)d_in[1];
    const float* cooc   = (const float*)d_in[2];
    int B = in_sizes[0] / Ccand;
    float* out_ids    = (float*)d_out;
    float* out_scores = out_ids + (size_t)B * Tgt;
    int blocks = (B + 3) / 4;
    hipLaunchKernelGGL(cooc_expand, dim3(blocks), dim3(256), 0, stream,
                       ids, scores, cooc, out_ids, out_scores, B);
}